// Round 2
// baseline (673.711 us; speedup 1.0000x reference)
//
#include <hip/hip_runtime.h>

#define N_NODES 8192
#define CAP 128          // neighbor capacity; Binomial(8192,1/256): P(deg>128) ~ 0
#define SCAN_BLOCKS 2048 // 4 rows/block, 1 row per wave
#define ENC_BLOCKS 256   // 32 nodes/block
#define TILE 32
constexpr int AST = 132; // activation LDS row stride (floats), 16B-aligned, padded
constexpr int WST = 129; // weight LDS row stride (k-major), +1 pad

// ---------------------------------------------------------------------------
// Fused LDS-resident MLP layer for a TILE of 32 nodes.
// A = [A0 | A1] split at KSPLIT (A1 unused when KSPLIT==K). W is F x K
// row-major in global; staged k-major in chunks of 32. Output: LDS and/or
// global, optional bias/relu/row-mask.
// ---------------------------------------------------------------------------
template <int K, int KSPLIT, int F, bool RELU, bool BIAS, bool MASK>
__device__ __forceinline__ void layer_op(
    const float (*__restrict__ A0)[AST], const float (*__restrict__ A1)[AST],
    float (*__restrict__ Aout)[AST], float (*__restrict__ Wb)[WST],
    const float* __restrict__ W, const float* __restrict__ bias,
    float* __restrict__ gout, const float* __restrict__ rowmask,
    int n0, int t) {
  constexpr int KC = 32;
  constexpr int NCH = K / KC;
  constexpr int RS = 256 / F;     // rows per sweep
  constexpr int RPT = TILE / RS;  // accumulators per thread
  const int c = t % F;
  const int rb = t / F;
  float acc[RPT];
#pragma unroll
  for (int i = 0; i < RPT; ++i) acc[i] = 0.f;

  for (int ch = 0; ch < NCH; ++ch) {
#pragma unroll
    for (int i = 0; i < (F * KC + 255) / 256; ++i) {  // stage W chunk, k-major
      int lin = t + i * 256;
      if ((F * KC) % 256 == 0 || lin < F * KC) {
        int k = lin % KC, f = lin / KC;
        Wb[k][f] = W[(size_t)f * K + ch * KC + k];
      }
    }
    __syncthreads();
    const float (*__restrict__ As)[AST] = (ch * KC < KSPLIT) ? A0 : A1;
    const int kb = (ch * KC < KSPLIT) ? ch * KC : ch * KC - KSPLIT;
#pragma unroll
    for (int kg = 0; kg < KC / 4; ++kg) {
      float w0 = Wb[kg * 4 + 0][c];
      float w1 = Wb[kg * 4 + 1][c];
      float w2 = Wb[kg * 4 + 2][c];
      float w3 = Wb[kg * 4 + 3][c];
#pragma unroll
      for (int i = 0; i < RPT; ++i) {
        const float4 a = *(const float4*)&As[rb + i * RS][kb + kg * 4];
        acc[i] = fmaf(a.x, w0, acc[i]);
        acc[i] = fmaf(a.y, w1, acc[i]);
        acc[i] = fmaf(a.z, w2, acc[i]);
        acc[i] = fmaf(a.w, w3, acc[i]);
      }
    }
    __syncthreads();
  }
#pragma unroll
  for (int i = 0; i < RPT; ++i) {
    float v = acc[i];
    if (BIAS) v += bias[c];
    if (RELU) v = fmaxf(v, 0.f);
    int node = n0 + rb + i * RS;
    if (MASK) v *= rowmask[node];
    if (Aout) Aout[rb + i * RS][c] = v;
    if (gout) gout[(size_t)node * F + c] = v;
  }
}

// ---------------------------------------------------------------------------
// Kernel 1: fused adj-scan (CSR build, ballot compaction) + encoder MLP.
// The two roles are independent; one grid overlaps them.
// ---------------------------------------------------------------------------
__global__ __launch_bounds__(256) void scan_encode_kernel(
    const float* __restrict__ adj, const float* __restrict__ x,
    const float* __restrict__ w1, const float* __restrict__ b1,
    const float* __restrict__ w2, const float* __restrict__ b2,
    const float* __restrict__ wg,
    int* __restrict__ cnt, int* __restrict__ nbr, float* __restrict__ dinv,
    float* __restrict__ h_out, float* __restrict__ msg_out) {
  __shared__ float bufA[TILE][AST];
  __shared__ float bufB[TILE][AST];
  __shared__ float Wb[32][WST];
  const int t = threadIdx.x;

  if (blockIdx.x < SCAN_BLOCKS) {
    // ---- scan role: 1 row per wave, ballot-based compaction, no atomics ----
    const int lane = t & 63;
    const int row = blockIdx.x * 4 + (t >> 6);
    const float4* rowp = (const float4*)(adj + (size_t)row * N_NODES);
    const unsigned long long lmask = (1ull << lane) - 1;
    int off = 0;
    for (int it = 0; it < N_NODES / 4 / 64; ++it) {
      const int idx4 = lane + it * 64;
      const float4 v = rowp[idx4];
      const int col = idx4 * 4;
      {
        unsigned long long m = __ballot(v.x != 0.f);
        if (m) { if (v.x != 0.f) { int p = off + __popcll(m & lmask); if (p < CAP) nbr[row * CAP + p] = col; } off += __popcll(m); }
      }
      {
        unsigned long long m = __ballot(v.y != 0.f);
        if (m) { if (v.y != 0.f) { int p = off + __popcll(m & lmask); if (p < CAP) nbr[row * CAP + p] = col + 1; } off += __popcll(m); }
      }
      {
        unsigned long long m = __ballot(v.z != 0.f);
        if (m) { if (v.z != 0.f) { int p = off + __popcll(m & lmask); if (p < CAP) nbr[row * CAP + p] = col + 2; } off += __popcll(m); }
      }
      {
        unsigned long long m = __ballot(v.w != 0.f);
        if (m) { if (v.w != 0.f) { int p = off + __popcll(m & lmask); if (p < CAP) nbr[row * CAP + p] = col + 3; } off += __popcll(m); }
      }
    }
    if (lane == 0) {
      cnt[row] = off;
      dinv[row] = rsqrtf((float)off + 1.0f);
    }
  } else {
    // ---- encoder role: x -> h1 -> h -> msg for 32 nodes ----
    const int n0 = (blockIdx.x - SCAN_BLOCKS) * TILE;
    {  // stage x tile: 32x32 floats = 256 float4, one per thread
      int row = t >> 3, k4 = (t & 7) * 4;
      *(float4*)&bufA[row][k4] = *(const float4*)&x[(size_t)(n0 + row) * 32 + k4];
    }
    layer_op<32, 32, 64, true, true, false>(bufA, nullptr, bufB, Wb, w1, b1, nullptr, nullptr, n0, t);
    layer_op<64, 64, 128, true, true, false>(bufB, nullptr, bufA, Wb, w2, b2, h_out, nullptr, n0, t);
    layer_op<128, 128, 128, false, false, false>(bufA, nullptr, nullptr, Wb, wg, nullptr, msg_out, nullptr, n0, t);
  }
}

// ---------------------------------------------------------------------------
// Kernel 2: g1 = relu(dinv_i * (dinv_i*msg_i + sum_j dinv_j*msg_j) + bg)
// ---------------------------------------------------------------------------
__global__ __launch_bounds__(128) void agg_kernel(
    const int* __restrict__ cnt, const int* __restrict__ nbr,
    const float* __restrict__ msg, const float* __restrict__ dinv,
    const float* __restrict__ bg, const float* __restrict__ adj,
    float* __restrict__ g1) {
  const int row = blockIdx.x;
  const int t = threadIdx.x;  // 0..127
  float acc = dinv[row] * msg[(size_t)row * 128 + t];  // self-loop
  const int c = cnt[row];
  if (c <= CAP) {
    int i = 0;
    for (; i + 4 <= c; i += 4) {
      int j0 = nbr[row * CAP + i + 0];
      int j1 = nbr[row * CAP + i + 1];
      int j2 = nbr[row * CAP + i + 2];
      int j3 = nbr[row * CAP + i + 3];
      float a0 = dinv[j0] * msg[(size_t)j0 * 128 + t];
      float a1 = dinv[j1] * msg[(size_t)j1 * 128 + t];
      float a2 = dinv[j2] * msg[(size_t)j2 * 128 + t];
      float a3 = dinv[j3] * msg[(size_t)j3 * 128 + t];
      acc += (a0 + a1) + (a2 + a3);
    }
    for (; i < c; ++i) {
      int j = nbr[row * CAP + i];
      acc += dinv[j] * msg[(size_t)j * 128 + t];
    }
  } else {  // statistically unreachable dense fallback
    for (int col = 0; col < N_NODES; ++col) {
      if (adj[(size_t)row * N_NODES + col] != 0.f) acc += dinv[col] * msg[(size_t)col * 128 + t];
    }
  }
  float v = fmaf(dinv[row], acc, bg[t]);
  g1[(size_t)row * 128 + t] = fmaxf(v, 0.f);
}

// ---------------------------------------------------------------------------
// Kernel 3: fused decoder g1 -> g2 -> p1([g2|h]) -> p2 -> out * mask
// ---------------------------------------------------------------------------
__global__ __launch_bounds__(256) void decode_kernel(
    const float* __restrict__ g1, const float* __restrict__ h,
    const float* __restrict__ wd, const float* __restrict__ bd,
    const float* __restrict__ wp1, const float* __restrict__ bp1,
    const float* __restrict__ wp2, const float* __restrict__ bp2,
    const float* __restrict__ wo, const float* __restrict__ bo,
    const float* __restrict__ mask, float* __restrict__ out) {
  __shared__ float bufA[TILE][AST];
  __shared__ float bufB[TILE][AST];
  __shared__ float bufH[TILE][AST];
  __shared__ float Wb[32][WST];
  const int t = threadIdx.x;
  const int n0 = blockIdx.x * TILE;
#pragma unroll
  for (int i = 0; i < 4; ++i) {  // stage g1 tile and h tile (32x128 each)
    int lin = t + i * 256;
    int row = lin >> 5, k4 = (lin & 31) * 4;
    *(float4*)&bufA[row][k4] = *(const float4*)&g1[(size_t)(n0 + row) * 128 + k4];
    *(float4*)&bufH[row][k4] = *(const float4*)&h[(size_t)(n0 + row) * 128 + k4];
  }
  layer_op<128, 128, 128, true, true, false>(bufA, nullptr, bufB, Wb, wd, bd, nullptr, nullptr, n0, t);   // g2
  layer_op<256, 128, 128, true, true, false>(bufB, bufH, bufA, Wb, wp1, bp1, nullptr, nullptr, n0, t);    // p1
  layer_op<128, 128, 64, true, true, false>(bufA, nullptr, bufB, Wb, wp2, bp2, nullptr, nullptr, n0, t);  // p2
  layer_op<64, 64, 8, false, true, true>(bufB, nullptr, nullptr, Wb, wo, bo, out, mask, n0, t);           // out
}

extern "C" void kernel_launch(void* const* d_in, const int* in_sizes, int n_in,
                              void* d_out, int out_size, void* d_ws, size_t ws_size,
                              hipStream_t stream) {
  const float* x    = (const float*)d_in[0];
  const float* adj  = (const float*)d_in[1];
  const float* mask = (const float*)d_in[2];
  const float* w1   = (const float*)d_in[3];
  const float* b1   = (const float*)d_in[4];
  const float* w2   = (const float*)d_in[5];
  const float* b2   = (const float*)d_in[6];
  const float* wg   = (const float*)d_in[7];
  const float* bg   = (const float*)d_in[8];
  const float* wd   = (const float*)d_in[9];
  const float* bd   = (const float*)d_in[10];
  const float* wp1  = (const float*)d_in[11];
  const float* bp1  = (const float*)d_in[12];
  const float* wp2  = (const float*)d_in[13];
  const float* bp2  = (const float*)d_in[14];
  const float* wo   = (const float*)d_in[15];
  const float* bo   = (const float*)d_in[16];
  float* out = (float*)d_out;

  float* ws = (float*)d_ws;
  float* h    = ws; ws += (size_t)N_NODES * 128;
  float* msg  = ws; ws += (size_t)N_NODES * 128;
  float* g1   = ws; ws += (size_t)N_NODES * 128;
  float* dinv = ws; ws += N_NODES;
  int* cnt = (int*)ws; ws += N_NODES;
  int* nbr = (int*)ws;  // N_NODES * CAP ints

  scan_encode_kernel<<<SCAN_BLOCKS + ENC_BLOCKS, 256, 0, stream>>>(
      adj, x, w1, b1, w2, b2, wg, cnt, nbr, dinv, h, msg);
  agg_kernel<<<N_NODES, 128, 0, stream>>>(cnt, nbr, msg, dinv, bg, adj, g1);
  decode_kernel<<<N_NODES / TILE, 256, 0, stream>>>(
      g1, h, wd, bd, wp1, bp1, wp2, bp2, wo, bo, mask, out);
}

// Round 3
// 600.638 us; speedup vs baseline: 1.1217x; 1.1217x over previous
//
#include <hip/hip_runtime.h>

#define N_NODES 8192
#define CAP 128   // neighbor capacity; Binomial(8192,1/256): P(deg>128) ~ 0
#define TILE 32
constexpr int AST = 132; // activation LDS row stride (floats), 16B-aligned, padded
constexpr int WST = 129; // weight LDS row stride (k-major), +1 pad

// ---------------------------------------------------------------------------
// Kernel 1: adj scan -> CSR. One row per 256-thread block. All 8 float4 loads
// issued up front (8 outstanding/wave = MLP); ballot compaction with one
// LDS atomic per non-empty ballot (~22% of ballots). Tiny LDS + low VGPR ->
// 8 blocks/CU, BW-bound.
// ---------------------------------------------------------------------------
__device__ __forceinline__ void emit_hits(float val, int col, int lane,
                                          unsigned long long lmask,
                                          int* s_cnt, int* nbr_row) {
  const bool hit = val != 0.f;
  const unsigned long long m = __ballot(hit);
  if (m) {
    int base;
    if (lane == 0) base = atomicAdd(s_cnt, (int)__popcll(m));
    base = __shfl(base, 0);
    if (hit) {
      int p = base + (int)__popcll(m & lmask);
      if (p < CAP) nbr_row[p] = col;
    }
  }
}

__global__ __launch_bounds__(256) void scan_kernel(
    const float* __restrict__ adj, int* __restrict__ cnt,
    int* __restrict__ nbr, float* __restrict__ dinv) {
  __shared__ int s_cnt;
  const int t = threadIdx.x;
  const int row = blockIdx.x;
  if (t == 0) s_cnt = 0;
  __syncthreads();
  const float4* rowp = (const float4*)(adj + (size_t)row * N_NODES);
  float4 v[8];
#pragma unroll
  for (int i = 0; i < 8; ++i) v[i] = rowp[t + i * 256];  // 8 loads in flight
  const int lane = t & 63;
  const unsigned long long lmask = (1ull << lane) - 1;
  int* nbr_row = nbr + row * CAP;
#pragma unroll
  for (int i = 0; i < 8; ++i) {
    const int col = (t + i * 256) * 4;
    emit_hits(v[i].x, col + 0, lane, lmask, &s_cnt, nbr_row);
    emit_hits(v[i].y, col + 1, lane, lmask, &s_cnt, nbr_row);
    emit_hits(v[i].z, col + 2, lane, lmask, &s_cnt, nbr_row);
    emit_hits(v[i].w, col + 3, lane, lmask, &s_cnt, nbr_row);
  }
  __syncthreads();
  if (t == 0) {
    cnt[row] = s_cnt;
    dinv[row] = rsqrtf((float)s_cnt + 1.0f);
  }
}

// ---------------------------------------------------------------------------
// Fused LDS-resident MLP layer for a TILE of 32 nodes (unchanged from R2).
// ---------------------------------------------------------------------------
template <int K, int KSPLIT, int F, bool RELU, bool BIAS, bool MASK>
__device__ __forceinline__ void layer_op(
    const float (*__restrict__ A0)[AST], const float (*__restrict__ A1)[AST],
    float (*__restrict__ Aout)[AST], float (*__restrict__ Wb)[WST],
    const float* __restrict__ W, const float* __restrict__ bias,
    float* __restrict__ gout, const float* __restrict__ rowmask,
    int n0, int t) {
  constexpr int KC = 32;
  constexpr int NCH = K / KC;
  constexpr int RS = 256 / F;     // rows per sweep
  constexpr int RPT = TILE / RS;  // accumulators per thread
  const int c = t % F;
  const int rb = t / F;
  float acc[RPT];
#pragma unroll
  for (int i = 0; i < RPT; ++i) acc[i] = 0.f;

  for (int ch = 0; ch < NCH; ++ch) {
#pragma unroll
    for (int i = 0; i < (F * KC + 255) / 256; ++i) {  // stage W chunk, k-major
      int lin = t + i * 256;
      if ((F * KC) % 256 == 0 || lin < F * KC) {
        int k = lin % KC, f = lin / KC;
        Wb[k][f] = W[(size_t)f * K + ch * KC + k];
      }
    }
    __syncthreads();
    const float (*__restrict__ As)[AST] = (ch * KC < KSPLIT) ? A0 : A1;
    const int kb = (ch * KC < KSPLIT) ? ch * KC : ch * KC - KSPLIT;
#pragma unroll
    for (int kg = 0; kg < KC / 4; ++kg) {
      float w0 = Wb[kg * 4 + 0][c];
      float w1 = Wb[kg * 4 + 1][c];
      float w2 = Wb[kg * 4 + 2][c];
      float w3 = Wb[kg * 4 + 3][c];
#pragma unroll
      for (int i = 0; i < RPT; ++i) {
        const float4 a = *(const float4*)&As[rb + i * RS][kb + kg * 4];
        acc[i] = fmaf(a.x, w0, acc[i]);
        acc[i] = fmaf(a.y, w1, acc[i]);
        acc[i] = fmaf(a.z, w2, acc[i]);
        acc[i] = fmaf(a.w, w3, acc[i]);
      }
    }
    __syncthreads();
  }
#pragma unroll
  for (int i = 0; i < RPT; ++i) {
    float v = acc[i];
    if (BIAS) v += bias[c];
    if (RELU) v = fmaxf(v, 0.f);
    int node = n0 + rb + i * RS;
    if (MASK) v *= rowmask[node];
    if (Aout) Aout[rb + i * RS][c] = v;
    if (gout) gout[(size_t)node * F + c] = v;
  }
}

// ---------------------------------------------------------------------------
// Kernel 2: encoder x -> h1 -> h -> msg (standalone, 256 blocks x 32 nodes)
// ---------------------------------------------------------------------------
__global__ __launch_bounds__(256) void encode_kernel(
    const float* __restrict__ x,
    const float* __restrict__ w1, const float* __restrict__ b1,
    const float* __restrict__ w2, const float* __restrict__ b2,
    const float* __restrict__ wg,
    float* __restrict__ h_out, float* __restrict__ msg_out) {
  __shared__ float bufA[TILE][AST];
  __shared__ float bufB[TILE][AST];
  __shared__ float Wb[32][WST];
  const int t = threadIdx.x;
  const int n0 = blockIdx.x * TILE;
  {  // stage x tile: 32x32 floats = 256 float4, one per thread
    int row = t >> 3, k4 = (t & 7) * 4;
    *(float4*)&bufA[row][k4] = *(const float4*)&x[(size_t)(n0 + row) * 32 + k4];
  }
  layer_op<32, 32, 64, true, true, false>(bufA, nullptr, bufB, Wb, w1, b1, nullptr, nullptr, n0, t);
  layer_op<64, 64, 128, true, true, false>(bufB, nullptr, bufA, Wb, w2, b2, h_out, nullptr, n0, t);
  layer_op<128, 128, 128, false, false, false>(bufA, nullptr, nullptr, Wb, wg, nullptr, msg_out, nullptr, n0, t);
}

// ---------------------------------------------------------------------------
// Kernel 3: g1 = relu(dinv_i * (dinv_i*msg_i + sum_j dinv_j*msg_j) + bg)
// ---------------------------------------------------------------------------
__global__ __launch_bounds__(128) void agg_kernel(
    const int* __restrict__ cnt, const int* __restrict__ nbr,
    const float* __restrict__ msg, const float* __restrict__ dinv,
    const float* __restrict__ bg, const float* __restrict__ adj,
    float* __restrict__ g1) {
  const int row = blockIdx.x;
  const int t = threadIdx.x;  // 0..127
  float acc = dinv[row] * msg[(size_t)row * 128 + t];  // self-loop
  const int c = cnt[row];
  if (c <= CAP) {
    int i = 0;
    for (; i + 4 <= c; i += 4) {
      int j0 = nbr[row * CAP + i + 0];
      int j1 = nbr[row * CAP + i + 1];
      int j2 = nbr[row * CAP + i + 2];
      int j3 = nbr[row * CAP + i + 3];
      float a0 = dinv[j0] * msg[(size_t)j0 * 128 + t];
      float a1 = dinv[j1] * msg[(size_t)j1 * 128 + t];
      float a2 = dinv[j2] * msg[(size_t)j2 * 128 + t];
      float a3 = dinv[j3] * msg[(size_t)j3 * 128 + t];
      acc += (a0 + a1) + (a2 + a3);
    }
    for (; i < c; ++i) {
      int j = nbr[row * CAP + i];
      acc += dinv[j] * msg[(size_t)j * 128 + t];
    }
  } else {  // statistically unreachable dense fallback
    for (int col = 0; col < N_NODES; ++col) {
      if (adj[(size_t)row * N_NODES + col] != 0.f) acc += dinv[col] * msg[(size_t)col * 128 + t];
    }
  }
  float v = fmaf(dinv[row], acc, bg[t]);
  g1[(size_t)row * 128 + t] = fmaxf(v, 0.f);
}

// ---------------------------------------------------------------------------
// Kernel 4: fused decoder g1 -> g2 -> p1([g2|h]) -> p2 -> out * mask
// ---------------------------------------------------------------------------
__global__ __launch_bounds__(256) void decode_kernel(
    const float* __restrict__ g1, const float* __restrict__ h,
    const float* __restrict__ wd, const float* __restrict__ bd,
    const float* __restrict__ wp1, const float* __restrict__ bp1,
    const float* __restrict__ wp2, const float* __restrict__ bp2,
    const float* __restrict__ wo, const float* __restrict__ bo,
    const float* __restrict__ mask, float* __restrict__ out) {
  __shared__ float bufA[TILE][AST];
  __shared__ float bufB[TILE][AST];
  __shared__ float bufH[TILE][AST];
  __shared__ float Wb[32][WST];
  const int t = threadIdx.x;
  const int n0 = blockIdx.x * TILE;
#pragma unroll
  for (int i = 0; i < 4; ++i) {  // stage g1 tile and h tile (32x128 each)
    int lin = t + i * 256;
    int row = lin >> 5, k4 = (lin & 31) * 4;
    *(float4*)&bufA[row][k4] = *(const float4*)&g1[(size_t)(n0 + row) * 128 + k4];
    *(float4*)&bufH[row][k4] = *(const float4*)&h[(size_t)(n0 + row) * 128 + k4];
  }
  layer_op<128, 128, 128, true, true, false>(bufA, nullptr, bufB, Wb, wd, bd, nullptr, nullptr, n0, t);   // g2
  layer_op<256, 128, 128, true, true, false>(bufB, bufH, bufA, Wb, wp1, bp1, nullptr, nullptr, n0, t);    // p1
  layer_op<128, 128, 64, true, true, false>(bufA, nullptr, bufB, Wb, wp2, bp2, nullptr, nullptr, n0, t);  // p2
  layer_op<64, 64, 8, false, true, true>(bufB, nullptr, nullptr, Wb, wo, bo, out, mask, n0, t);           // out
}

extern "C" void kernel_launch(void* const* d_in, const int* in_sizes, int n_in,
                              void* d_out, int out_size, void* d_ws, size_t ws_size,
                              hipStream_t stream) {
  const float* x    = (const float*)d_in[0];
  const float* adj  = (const float*)d_in[1];
  const float* mask = (const float*)d_in[2];
  const float* w1   = (const float*)d_in[3];
  const float* b1   = (const float*)d_in[4];
  const float* w2   = (const float*)d_in[5];
  const float* b2   = (const float*)d_in[6];
  const float* wg   = (const float*)d_in[7];
  const float* bg   = (const float*)d_in[8];
  const float* wd   = (const float*)d_in[9];
  const float* bd   = (const float*)d_in[10];
  const float* wp1  = (const float*)d_in[11];
  const float* bp1  = (const float*)d_in[12];
  const float* wp2  = (const float*)d_in[13];
  const float* bp2  = (const float*)d_in[14];
  const float* wo   = (const float*)d_in[15];
  const float* bo   = (const float*)d_in[16];
  float* out = (float*)d_out;

  float* ws = (float*)d_ws;
  float* h    = ws; ws += (size_t)N_NODES * 128;
  float* msg  = ws; ws += (size_t)N_NODES * 128;
  float* g1   = ws; ws += (size_t)N_NODES * 128;
  float* dinv = ws; ws += N_NODES;
  int* cnt = (int*)ws; ws += N_NODES;
  int* nbr = (int*)ws;  // N_NODES * CAP ints

  scan_kernel<<<N_NODES, 256, 0, stream>>>(adj, cnt, nbr, dinv);
  encode_kernel<<<N_NODES / TILE, 256, 0, stream>>>(x, w1, b1, w2, b2, wg, h, msg);
  agg_kernel<<<N_NODES, 128, 0, stream>>>(cnt, nbr, msg, dinv, bg, adj, g1);
  decode_kernel<<<N_NODES / TILE, 256, 0, stream>>>(
      g1, h, wd, bd, wp1, bp1, wp2, bp2, wo, bo, mask, out);
}